// Round 17
// baseline (410.417 us; speedup 1.0000x reference)
//
#include <hip/hip_runtime.h>

// Harness-provided kernel symbol kept (not required to do work).
__global__ void GraphEncoder_20555713479231_kernel() {}

using hfrag8 = __attribute__((ext_vector_type(8))) _Float16;  // 8 f16 (4 VGPRs)
using facc4  = __attribute__((ext_vector_type(4))) float;     // 4 fp32 acc
using h2     = __attribute__((ext_vector_type(2))) _Float16;  // packed f16 pair

__device__ __forceinline__ unsigned short f2h_bits(float f) {
  union { _Float16 h; unsigned short u; } c;
  c.h = (_Float16)f;
  return c.u;
}
__device__ __forceinline__ unsigned packh(float a, float b) {
  return (unsigned)f2h_bits(a) | ((unsigned)f2h_bits(b) << 16);
}
__device__ __forceinline__ h2 u2h(unsigned u) {
  union { unsigned u; h2 h; } c;
  c.u = u;
  return c.h;
}
__device__ __forceinline__ unsigned h22u(h2 h) {
  union { h2 h; unsigned u; } c;
  c.h = h;
  return c.u;
}
__device__ __forceinline__ float h2f_lo(unsigned u) { return (float)u2h(u).x; }
__device__ __forceinline__ float h2f_hi(unsigned u) { return (float)u2h(u).y; }

// ---------------- CSR build ----------------
__global__ __launch_bounds__(256) void k_hist(const int* __restrict__ dst,
                                              int* __restrict__ deg, int e) {
  int i = blockIdx.x * blockDim.x + threadIdx.x;
  if (i < e) atomicAdd(&deg[dst[i]], 1);
}

// parallel scan pass 1: per-block exclusive scan of (deg[i]+1); block totals to bsum
__global__ __launch_bounds__(256) void k_scan1(const int* __restrict__ deg,
                                               int* __restrict__ off,
                                               int* __restrict__ bsum, int n) {
  __shared__ int wsum[4];
  int tid = threadIdx.x;
  int gid = blockIdx.x * 256 + tid;
  int lane = tid & 63, wid = tid >> 6;
  int v = (gid < n) ? (deg[gid] + 1) : 0;
  int x = v;
  #pragma unroll
  for (int d = 1; d < 64; d <<= 1) {
    int t = __shfl_up(x, d);
    if (lane >= d) x += t;
  }
  if (lane == 63) wsum[wid] = x;
  __syncthreads();
  int wpre = 0;
  for (int k = 0; k < wid; ++k) wpre += wsum[k];
  if (gid < n) off[gid] = wpre + x - v;
  if (tid == 0) {
    int t = 0;
    #pragma unroll
    for (int k = 0; k < 4; ++k) t += wsum[k];
    bsum[blockIdx.x] = t;
  }
}

// pass 2: single block scans block sums (nb <= 256) exclusive; total -> off[n]
__global__ __launch_bounds__(256) void k_scan2(int* __restrict__ bsum,
                                               int* __restrict__ off, int nb, int n) {
  __shared__ int wsum[4];
  int tid = threadIdx.x;
  int lane = tid & 63, wid = tid >> 6;
  int v = (tid < nb) ? bsum[tid] : 0;
  int x = v;
  #pragma unroll
  for (int d = 1; d < 64; d <<= 1) {
    int t = __shfl_up(x, d);
    if (lane >= d) x += t;
  }
  if (lane == 63) wsum[wid] = x;
  __syncthreads();
  int wpre = 0;
  for (int k = 0; k < wid; ++k) wpre += wsum[k];
  if (tid < nb) bsum[tid] = wpre + x - v;
  if (tid == 0) {
    int t = 0;
    #pragma unroll
    for (int k = 0; k < 4; ++k) t += wsum[k];
    off[n] = t;
  }
}

// pass 3: add block prefix; also init self-loop slot and fill cursor (fused initpos)
__global__ __launch_bounds__(256) void k_scan3(int* __restrict__ off,
                                               const int* __restrict__ bsum,
                                               int* __restrict__ pos,
                                               int* __restrict__ csr, int n) {
  int gid = blockIdx.x * 256 + threadIdx.x;
  if (gid < n) {
    int o = off[gid] + bsum[blockIdx.x];
    off[gid] = o;
    csr[o] = gid;  // self-loop occupies first slot
    pos[gid] = o + 1;
  }
}

__global__ __launch_bounds__(256) void k_fill(const int* __restrict__ src,
                                              const int* __restrict__ dst,
                                              int* __restrict__ pos,
                                              int* __restrict__ csr, int e) {
  int i = blockIdx.x * blockDim.x + threadIdx.x;
  if (i < e) {
    int d = dst[i];
    int p = atomicAdd(&pos[d], 1);
    csr[p] = src[i];
  }
}

// ---------------- pack weights (3 layers) + layer-0 tables + bit-packed types ------
__global__ __launch_bounds__(256)
void k_pack3(const float* __restrict__ wl1, const float* __restrict__ wr1,
             const float* __restrict__ wl2, const float* __restrict__ wr2,
             const float* __restrict__ wl3, const float* __restrict__ wr3,
             const float* __restrict__ emb,
             const float* __restrict__ wl0, const float* __restrict__ wr0,
             const int* __restrict__ types, int n,
             unsigned short* __restrict__ bp,
             unsigned* __restrict__ tlb, float* __restrict__ trf,
             unsigned* __restrict__ ptypes) {
  int b = blockIdx.x;
  if (b < 384) {
    int idx = b * 256 + threadIdx.x;  // 0..98303
    int layer = idx >> 15;
    int r = idx & 32767;
    int j = r & 7, lane = (r >> 3) & 63, ct = (r >> 9) & 15, t = r >> 13;
    int k = t * 32 + (lane >> 4) * 8 + j;
    int c = ct * 16 + (lane & 15);
    const float* wl = (layer == 0) ? wl1 : ((layer == 1) ? wl2 : wl3);
    const float* wr = (layer == 0) ? wr1 : ((layer == 1) ? wr2 : wr3);
    float v = (c < 128) ? wl[k * 128 + c] : wr[k * 128 + (c - 128)];
    bp[idx] = f2h_bits(v);
  } else if (b == 384) {
    int tid = threadIdx.x;
    if (tid >= 192) return;
    int row = tid >> 6, cp = tid & 63, c0 = cp * 2;
    float al0 = 0.f, al1 = 0.f, ar0 = 0.f, ar1 = 0.f;
    #pragma unroll
    for (int k = 0; k < 16; ++k) {
      float ev = emb[row * 16 + k];
      al0 += ev * wl0[k * 128 + c0];
      al1 += ev * wl0[k * 128 + c0 + 1];
      ar0 += ev * wr0[k * 128 + c0];
      ar1 += ev * wr0[k * 128 + c0 + 1];
    }
    tlb[row * 64 + cp] = packh(al0, al1);
    *(float2*)(trf + row * 128 + c0) = make_float2(ar0, ar1);
  } else {
    int i = (b - 385) * 256 + threadIdx.x;
    int npk = (n + 15) >> 4;
    if (i < npk) {
      unsigned pw = 0;
      #pragma unroll
      for (int j = 0; j < 16; ++j) {
        int u = i * 16 + j;
        int ty = (u < n) ? (types[u] & 3) : 3;
        pw |= ((unsigned)ty) << (2 * j);
      }
      ptypes[i] = pw;
    }
  }
}

// ---------------- layer-0 aggregation via neighbor-type histogram ----------------
__global__ __launch_bounds__(256)
void k_agg0(const int* __restrict__ off, const int* __restrict__ csr,
            const unsigned* __restrict__ ptypes,
            const unsigned* __restrict__ tlb, const float* __restrict__ trf,
            const float* __restrict__ att, const float* __restrict__ bias,
            const float* __restrict__ lng, const float* __restrict__ lnb,
            unsigned* __restrict__ yout, int n) {
  int v = (blockIdx.x * blockDim.x + threadIdx.x) >> 6;
  int lane = threadIdx.x & 63;
  if (v >= n) return;
  v = __builtin_amdgcn_readfirstlane(v);
  int beg = off[v], end = off[v + 1];
  int c0 = 0, c1 = 0, c2 = 0;
  for (int base = beg; base < end; base += 64) {
    int e = base + lane;
    bool act = e < end;
    int u = act ? csr[e] : 0;
    unsigned pw = ptypes[u >> 4];
    int ty = act ? (int)((pw >> ((u & 15) * 2)) & 3) : 3;
    c0 += __popcll(__ballot(ty == 0));
    c1 += __popcll(__ballot(ty == 1));
    c2 += __popcll(__ballot(ty == 2));
  }
  float cnt[3] = {(float)c0, (float)c1, (float)c2};
  int f0 = lane * 2;
  unsigned pwv = ptypes[v >> 4];
  int tyv = (int)((pwv >> ((v & 15) * 2)) & 3);
  float2 xrv = *(const float2*)(trf + tyv * 128 + f0);
  float a0 = att[f0], a1 = att[f0 + 1];
  float s = 0.f, O0 = 0.f, O1 = 0.f;
  #pragma unroll
  for (int ty = 0; ty < 3; ++ty) {
    unsigned p = tlb[ty * 64 + lane];
    float x0 = h2f_lo(p), x1 = h2f_hi(p);
    float t0 = x0 + xrv.x; t0 = t0 > 0.f ? t0 : 0.2f * t0;
    float t1 = x1 + xrv.y; t1 = t1 > 0.f ? t1 : 0.2f * t1;
    float c = t0 * a0 + t1 * a1;
    c += __shfl_xor(c, 1);
    c += __shfl_xor(c, 2);
    c += __shfl_xor(c, 4);
    c += __shfl_xor(c, 8);
    float w = cnt[ty] * __expf(c);
    s += w;
    O0 = fmaf(w, x0, O0);
    O1 = fmaf(w, x1, O1);
  }
  float inv = 1.f / s;
  float o0 = O0 * inv + bias[f0];
  float o1 = O1 * inv + bias[f0 + 1];
  float sum = o0 + o1, sq = o0 * o0 + o1 * o1;
  #pragma unroll
  for (int d2 = 1; d2 < 64; d2 <<= 1) {
    sum += __shfl_xor(sum, d2);
    sq += __shfl_xor(sq, d2);
  }
  float mu = sum * (1.f / 128.f);
  float var = sq * (1.f / 128.f) - mu * mu;
  float rstd = rsqrtf(var + 1e-5f);
  float y0 = fmaxf((o0 - mu) * rstd * lng[f0] + lnb[f0], 0.f);
  float y1 = fmaxf((o1 - mu) * rstd * lng[f0 + 1] + lnb[f0 + 1], 0.f);
  yout[(size_t)v * 64 + lane] = packh(y0, y1);
}

// ---------------- GEMM (MFMA f16): x(Nx128 f16 packed) @ [Wl|Wr] -> xl, xr (f16 packed) ----
__global__ __launch_bounds__(256)
void k_gemm(const unsigned* __restrict__ x, const unsigned short* __restrict__ bp,
            unsigned* __restrict__ xlo, unsigned* __restrict__ xro, int nstrips, int n) {
  int wave = (blockIdx.x * 256 + threadIdx.x) >> 6;
  int lane = threadIdx.x & 63;
  if (wave >= nstrips) return;
  int r0 = wave * 16;
  int row = r0 + (lane & 15);
  if (row >= n) row = n - 1;
  int quad = lane >> 4;
  const unsigned* ap = x + (size_t)row * 64;
  hfrag8 a[4];
  #pragma unroll
  for (int t = 0; t < 4; ++t) a[t] = *(const hfrag8*)(ap + t * 16 + quad * 4);
  unsigned short* xloS = (unsigned short*)xlo;
  unsigned short* xroS = (unsigned short*)xro;
  int rbase = r0 + quad * 4;
  #pragma unroll
  for (int ct = 0; ct < 16; ++ct) {
    facc4 acc = {0.f, 0.f, 0.f, 0.f};
    #pragma unroll
    for (int t = 0; t < 4; ++t) {
      hfrag8 b = *(const hfrag8*)(bp + (size_t)(((t * 16 + ct) * 64 + lane) * 8));
      acc = __builtin_amdgcn_mfma_f32_16x16x32_f16(a[t], b, acc, 0, 0, 0);
    }
    int col = (ct & 7) * 16 + (lane & 15);
    unsigned short* dstp = (ct < 8) ? xloS : xroS;
    #pragma unroll
    for (int i = 0; i < 4; ++i) {
      int r = rbase + i;
      if (r < n) dstp[(size_t)r * 128 + col] = f2h_bits(acc[i]);
    }
  }
}

// ---------------- fused aggregate + bias + residual + LN + ReLU (f16 packed) ----------
// one wave per dst node; lane owns features 2*lane, 2*lane+1; activations f16 pairs.
// Unroll-4: edges (e..e+3) ride TWO independent packed-logit shuffle trees per
// iteration, halving the serial bpermute latency per edge. Indices are
// wave-uniform scalar loads (s_min clamps); rows prefetched 8 deep.
__global__ __launch_bounds__(256)
void k_agg(const int* __restrict__ off, const int* __restrict__ csr,
           const unsigned* __restrict__ xl, const unsigned* __restrict__ xr,
           const float* __restrict__ att, const float* __restrict__ bias,
           const unsigned* __restrict__ xres,
           const float* __restrict__ lng, const float* __restrict__ lnb,
           unsigned* __restrict__ ybf, float* __restrict__ yf32, int n, int wide) {
  int v = (blockIdx.x * blockDim.x + threadIdx.x) >> 6;
  int lane = threadIdx.x & 63;
  if (v >= n) return;
  v = __builtin_amdgcn_readfirstlane(v);
  int f0 = lane * 2;
  h2 a2;
  a2.x = (_Float16)att[f0];
  a2.y = (_Float16)att[f0 + 1];
  h2 r2 = u2h(xr[(size_t)v * 64 + lane]);
  h2 k02 = {(_Float16)0.2f, (_Float16)0.2f};
  int beg = off[v], end = off[v + 1];
  int last = end - 1;
  const unsigned* xlp = xl + lane;  // row r at xlp[r*64]
  unsigned P[8];
  #pragma unroll
  for (int j = 0; j < 8; ++j) P[j] = xlp[(size_t)csr[min(beg + j, last)] * 64];
  float sa = 0.f, sb = 0.f;
  h2 Oa = {(_Float16)0.f, (_Float16)0.f};
  h2 Ob = {(_Float16)0.f, (_Float16)0.f};
  for (int e = beg; e < end; e += 4) {
    unsigned np[4];
    #pragma unroll
    for (int j = 0; j < 4; ++j) np[j] = xlp[(size_t)csr[min(e + 8 + j, last)] * 64];
    h2 x0 = u2h(P[0]), x1 = u2h(P[1]), x2 = u2h(P[2]), x3 = u2h(P[3]);
    h2 t0 = x0 + r2, t1 = x1 + r2, t2 = x2 + r2, t3 = x3 + r2;
    t0 = __builtin_elementwise_max(t0, t0 * k02);
    t1 = __builtin_elementwise_max(t1, t1 * k02);
    t2 = __builtin_elementwise_max(t2, t2 * k02);
    t3 = __builtin_elementwise_max(t3, t3 * k02);
    h2 d0 = t0 * a2, d1 = t1 * a2, d2 = t2 * a2, d3 = t3 * a2;
    h2 c01, c23;
    c01.x = d0.x + d0.y; c01.y = d1.x + d1.y;
    c23.x = d2.x + d2.y; c23.y = d3.x + d3.y;
    unsigned u01 = h22u(c01), u23 = h22u(c23);
    u01 = h22u(u2h(u01) + u2h((unsigned)__shfl_xor((int)u01, 1)));
    u23 = h22u(u2h(u23) + u2h((unsigned)__shfl_xor((int)u23, 1)));
    u01 = h22u(u2h(u01) + u2h((unsigned)__shfl_xor((int)u01, 2)));
    u23 = h22u(u2h(u23) + u2h((unsigned)__shfl_xor((int)u23, 2)));
    u01 = h22u(u2h(u01) + u2h((unsigned)__shfl_xor((int)u01, 4)));
    u23 = h22u(u2h(u23) + u2h((unsigned)__shfl_xor((int)u23, 4)));
    u01 = h22u(u2h(u01) + u2h((unsigned)__shfl_xor((int)u01, 8)));
    u23 = h22u(u2h(u23) + u2h((unsigned)__shfl_xor((int)u23, 8)));
    if (wide) {
      u01 = h22u(u2h(u01) + u2h((unsigned)__shfl_xor((int)u01, 16)));
      u23 = h22u(u2h(u23) + u2h((unsigned)__shfl_xor((int)u23, 16)));
      u01 = h22u(u2h(u01) + u2h((unsigned)__shfl_xor((int)u01, 32)));
      u23 = h22u(u2h(u23) + u2h((unsigned)__shfl_xor((int)u23, 32)));
    }
    h2 f01 = u2h(u01), f23 = u2h(u23);
    float w0 = __expf((float)f01.x);
    float w1 = (e + 1 < end) ? __expf((float)f01.y) : 0.f;
    float w2 = (e + 2 < end) ? __expf((float)f23.x) : 0.f;
    float w3 = (e + 3 < end) ? __expf((float)f23.y) : 0.f;
    sa += w0 + w2;
    sb += w1 + w3;
    _Float16 w0h = (_Float16)w0, w1h = (_Float16)w1;
    _Float16 w2h = (_Float16)w2, w3h = (_Float16)w3;
    h2 w02 = {w0h, w0h}, w12 = {w1h, w1h}, w22 = {w2h, w2h}, w32 = {w3h, w3h};
    Oa = w02 * x0 + Oa;
    Ob = w12 * x1 + Ob;
    Oa = w22 * x2 + Oa;
    Ob = w32 * x3 + Ob;
    #pragma unroll
    for (int j = 0; j < 4; ++j) P[j] = P[j + 4];
    #pragma unroll
    for (int j = 0; j < 4; ++j) P[j + 4] = np[j];
  }
  float s = sa + sb;
  float O0 = (float)Oa.x + (float)Ob.x;
  float O1 = (float)Oa.y + (float)Ob.y;
  float inv = 1.f / s;
  float o0 = O0 * inv + bias[f0];
  float o1 = O1 * inv + bias[f0 + 1];
  if (xres) {
    unsigned rs = xres[(size_t)v * 64 + lane];
    o0 += h2f_lo(rs);
    o1 += h2f_hi(rs);
  }
  float sum = o0 + o1, sq = o0 * o0 + o1 * o1;
  #pragma unroll
  for (int d2 = 1; d2 < 64; d2 <<= 1) {
    sum += __shfl_xor(sum, d2);
    sq += __shfl_xor(sq, d2);
  }
  float mu = sum * (1.f / 128.f);
  float var = sq * (1.f / 128.f) - mu * mu;
  float rstd = rsqrtf(var + 1e-5f);
  float y0 = fmaxf((o0 - mu) * rstd * lng[f0] + lnb[f0], 0.f);
  float y1 = fmaxf((o1 - mu) * rstd * lng[f0 + 1] + lnb[f0 + 1], 0.f);
  if (yf32) {
    *(float2*)(yf32 + (size_t)v * 128 + f0) = make_float2(y0, y1);
  } else {
    ybf[(size_t)v * 64 + lane] = packh(y0, y1);
  }
}

// ---------------- launch ----------------
extern "C" void kernel_launch(void* const* d_in, const int* in_sizes, int n_in,
                              void* d_out, int out_size, void* d_ws, size_t ws_size,
                              hipStream_t stream) {
  (void)n_in; (void)out_size; (void)ws_size;
  const int* node_types = (const int*)d_in[0];
  const int* edge_index = (const int*)d_in[1];
  const float* emb = (const float*)d_in[2];
  const float* Wl0 = (const float*)d_in[3];
  const float* Wr0 = (const float*)d_in[4];
  const float* att0 = (const float*)d_in[5];
  const float* b0 = (const float*)d_in[6];
  const float* Wl1 = (const float*)d_in[7];
  const float* Wr1 = (const float*)d_in[8];
  const float* att1 = (const float*)d_in[9];
  const float* b1 = (const float*)d_in[10];
  const float* Wl2 = (const float*)d_in[11];
  const float* Wr2 = (const float*)d_in[12];
  const float* att2 = (const float*)d_in[13];
  const float* b2 = (const float*)d_in[14];
  const float* Wl3 = (const float*)d_in[15];
  const float* Wr3 = (const float*)d_in[16];
  const float* att3 = (const float*)d_in[17];
  const float* b3 = (const float*)d_in[18];
  const float* lng = (const float*)d_in[19];
  const float* lnb = (const float*)d_in[20];

  int n = in_sizes[0];
  int e = in_sizes[1] / 2;
  const int* srcp = edge_index;
  const int* dstp = edge_index + e;
  int nblocks = (n + 255) / 256;

  // workspace carve (256-byte aligned chunks)
  char* wsp = (char*)d_ws;
  size_t ofs = 0;
  int* deg = (int*)(wsp + ofs); ofs += (((size_t)n * 4) + 255) & ~(size_t)255;
  int* off = (int*)(wsp + ofs); ofs += (((size_t)(n + 1) * 4) + 255) & ~(size_t)255;
  int* csr = (int*)(wsp + ofs); ofs += (((size_t)(e + n) * 4) + 255) & ~(size_t)255;
  int* bsum = (int*)(wsp + ofs); ofs += (((size_t)nblocks * 4) + 255) & ~(size_t)255;
  unsigned* xlb = (unsigned*)(wsp + ofs); ofs += (((size_t)n * 64 * 4) + 255) & ~(size_t)255;
  unsigned* xrb = (unsigned*)(wsp + ofs); ofs += (((size_t)n * 64 * 4) + 255) & ~(size_t)255;
  unsigned* xcur = (unsigned*)(wsp + ofs); ofs += (((size_t)n * 64 * 4) + 255) & ~(size_t)255;
  unsigned short* bp = (unsigned short*)(wsp + ofs); ofs += 3 * 65536;
  unsigned* tlb = (unsigned*)(wsp + ofs); ofs += 1024;
  float* trf = (float*)(wsp + ofs); ofs += 2048;
  unsigned* ptypes = (unsigned*)(wsp + ofs); ofs += ((((size_t)(n + 15) / 16) * 4) + 255) & ~(size_t)255;
  int* pos = deg;  // deg dead after scan; reuse as fill cursor

  // CSR build (graph identical across all 4 layers) + weight/type pack (independent)
  (void)hipMemsetAsync(deg, 0, (size_t)n * 4, stream);
  k_hist<<<(e + 255) / 256, 256, 0, stream>>>(dstp, deg, e);
  int npk = (n + 15) / 16;
  int packGrid = 385 + (npk + 255) / 256;
  k_pack3<<<packGrid, 256, 0, stream>>>(Wl1, Wr1, Wl2, Wr2, Wl3, Wr3,
                                        emb, Wl0, Wr0, node_types, n,
                                        bp, tlb, trf, ptypes);
  k_scan1<<<nblocks, 256, 0, stream>>>(deg, off, bsum, n);
  k_scan2<<<1, 256, 0, stream>>>(bsum, off, nblocks, n);
  k_scan3<<<nblocks, 256, 0, stream>>>(off, bsum, pos, csr, n);
  k_fill<<<(e + 255) / 256, 256, 0, stream>>>(srcp, dstp, pos, csr, e);

  int aggBlocks = (n * 64 + 255) / 256;  // one wave per node

  // layer 0: type-table aggregation (ballot histogram from packed types)
  k_agg0<<<aggBlocks, 256, 0, stream>>>(off, csr, ptypes, tlb, trf,
                                        att0, b0, lng, lnb, xcur, n);

  int nstrips = (n + 15) / 16;
  int gemmBlocks = (nstrips + 3) / 4;

  // layer 1
  k_gemm<<<gemmBlocks, 256, 0, stream>>>(xcur, bp, xlb, xrb, nstrips, n);
  k_agg<<<aggBlocks, 256, 0, stream>>>(off, csr, xlb, xrb, att1, b1, xcur,
                                       lng + 128, lnb + 128, xcur, (float*)0, n, 0);
  // layer 2
  k_gemm<<<gemmBlocks, 256, 0, stream>>>(xcur, bp + 32768, xlb, xrb, nstrips, n);
  k_agg<<<aggBlocks, 256, 0, stream>>>(off, csr, xlb, xrb, att2, b2, xcur,
                                       lng + 256, lnb + 256, xcur, (float*)0, n, 0);
  // layer 3 (single head, wide reduce; f32 output to d_out)
  k_gemm<<<gemmBlocks, 256, 0, stream>>>(xcur, bp + 65536, xlb, xrb, nstrips, n);
  k_agg<<<aggBlocks, 256, 0, stream>>>(off, csr, xlb, xrb, att3, b3, xcur,
                                       lng + 384, lnb + 384, (unsigned*)0, (float*)d_out, n, 1);
}